// Round 12
// baseline (178.635 us; speedup 1.0000x reference)
//
#include <hip/hip_runtime.h>
#include <math.h>

#define TN 4096
#define HN 2048
#define NB 32
#define NCH 9
#define NCODES 512
#define CDIM 64
#define TAU 1e-3f
#define PTS 256          // points per vq block
#define VQT 512          // vq threads per block

typedef _Float16 f16x8 __attribute__((ext_vector_type(8)));
typedef float f32x4 __attribute__((ext_vector_type(4)));

__device__ __forceinline__ float2 cmulf(float2 a, float2 b) {
    return make_float2(a.x * b.x - a.y * b.y, a.x * b.y + a.y * b.x);
}
__device__ __forceinline__ float2 f2add(float2 a, float2 b) {
    return make_float2(a.x + b.x, a.y + b.y);
}
__device__ __forceinline__ float2 f2sub(float2 a, float2 b) {
    return make_float2(a.x - b.x, a.y - b.y);
}

__device__ __forceinline__ unsigned long long packsi(float s, int i) {
    unsigned u = __float_as_uint(s);
    u = (u & 0x80000000u) ? ~u : (u | 0x80000000u);
    return ((unsigned long long)u << 32) | (unsigned)i;
}

__device__ __forceinline__ void gload_lds16(const void* g, void* l) {
    __builtin_amdgcn_global_load_lds(
        (const __attribute__((address_space(1))) unsigned int*)g,
        (__attribute__((address_space(3))) unsigned int*)l, 16, 0, 0);
}

// Fragment-tile unit index: [entity16-group][plane][s][hi16][l15], 16B units.
__device__ __forceinline__ size_t aunit(int pbase, int plane, int s, int hi16, int l15) {
    return ((size_t)(((pbase * 2 + plane) * 2 + s) * 4 + hi16) << 4) + l15;
}

// prep: bid<512 zero phases; bid 512..543: code fragment tiles; bid 544: norms.
__global__ __launch_bounds__(256) void prep_kernel(const float* __restrict__ cb,
                                                   float* __restrict__ cn,
                                                   f16x8* __restrict__ ctiles,
                                                   float* __restrict__ ph) {
    const int bid = blockIdx.x;
    const int tid = threadIdx.x;
    if (bid < 512) {
        ph[bid * 256 + tid] = 0.0f;
        return;
    }
    if (bid < 544) {
        const int u = (bid - 512) * 256 + tid;    // 8192 units
        const int l15 = u & 15;
        const int hi16 = (u >> 4) & 3;
        const int s = (u >> 6) & 1;
        const int plane = (u >> 7) & 1;
        const int cbase = u >> 8;
        const int code = cbase * 16 + l15;
        f16x8 out;
        #pragma unroll
        for (int e = 0; e < 8; ++e) {
            float c = cb[code * CDIM + 32 * s + 8 * hi16 + e];
            _Float16 hh = (_Float16)c;
            out[e] = plane ? (_Float16)(c - (float)hh) : hh;
        }
        ctiles[u] = out;
        return;
    }
    for (int k = tid; k < NCODES; k += 256) {
        const float4* c4 = (const float4*)(cb + (size_t)k * CDIM);
        float s = 0.0f;
        #pragma unroll
        for (int q = 0; q < 16; ++q) {
            float4 c = c4[q];
            s = fmaf(c.x, c.x, s);
            s = fmaf(c.y, c.y, s);
            s = fmaf(c.z, c.z, s);
            s = fmaf(c.w, c.w, s);
        }
        cn[k] = s;
    }
}

// Paired-row Hilbert (radix-4 Stockham) — exact r7 form (best measured).
#define HT 512
__global__ __launch_bounds__(HT) void hilbert_phase_kernel(
    const float* __restrict__ x, float* __restrict__ phases) {
    __shared__ float2 bufA[TN];
    __shared__ float2 bufB[TN];
    __shared__ float2 tw[HN];
    const int tid = threadIdx.x;
    const int row1 = 2 * blockIdx.x;
    const int row2 = row1 + 1;
    const int b1 = row1 / NCH;
    const int b2 = row2 / NCH;
    const float* xr1 = x + (size_t)row1 * TN;
    const float* xr2 = x + (size_t)row2 * TN;

    for (int i = tid; i < HN; i += HT) {
        float ang = -3.14159265358979323846f * ((float)i / (float)HN);
        float s, c;
        sincosf(ang, &s, &c);
        tw[i] = make_float2(c, s);
    }
    for (int i = tid; i < TN; i += HT) {
        bufA[i] = make_float2(xr1[i], xr2[i]);
    }
    __syncthreads();

    float2* src = bufA;
    float2* dst = bufB;
    for (int stage = 0; stage < 6; ++stage) {
        const int m = 1 << (2 * stage);
        for (int idx = tid; idx < 1024; idx += HT) {
            const int kk = idx & (m - 1);
            const int jm = idx - kk;
            float2 a0 = src[idx];
            float2 a1 = src[idx + 1024];
            float2 a2 = src[idx + 2048];
            float2 a3 = src[idx + 3072];
            float2 b0 = f2add(a0, a2);
            float2 b1 = f2add(a1, a3);
            float2 b2 = f2sub(a0, a2);
            float2 b3 = f2sub(a1, a3);
            float2 w1 = tw[jm];
            float2 w2 = tw[2 * jm];
            float2 w3 = cmulf(w1, w2);
            float2 y0 = f2add(b0, b1);
            float2 mi = make_float2(b2.x + b3.y, b2.y - b3.x);
            float2 pi_ = make_float2(b2.x - b3.y, b2.y + b3.x);
            dst[4 * jm + kk]         = y0;
            dst[4 * jm + kk + m]     = cmulf(mi, w1);
            dst[4 * jm + kk + 2 * m] = cmulf(f2sub(b0, b1), w2);
            dst[4 * jm + kk + 3 * m] = cmulf(pi_, w3);
        }
        __syncthreads();
        float2* t0 = src; src = dst; dst = t0;
    }
    const float inv = 1.0f / (float)TN;
    for (int i = tid; i < TN; i += HT) {
        float sc;
        if (i == 0 || i == HN) sc = inv;
        else if (i < HN) sc = 2.0f * inv;
        else sc = 0.0f;
        float2 v = src[i];
        v.x *= sc; v.y *= sc;
        src[i] = v;
    }
    __syncthreads();
    for (int stage = 0; stage < 6; ++stage) {
        const int m = 1 << (2 * stage);
        for (int idx = tid; idx < 1024; idx += HT) {
            const int kk = idx & (m - 1);
            const int jm = idx - kk;
            float2 a0 = src[idx];
            float2 a1 = src[idx + 1024];
            float2 a2 = src[idx + 2048];
            float2 a3 = src[idx + 3072];
            float2 b0 = f2add(a0, a2);
            float2 b1 = f2add(a1, a3);
            float2 b2 = f2sub(a0, a2);
            float2 b3 = f2sub(a1, a3);
            float2 w1 = tw[jm];      w1.y = -w1.y;
            float2 w2 = tw[2 * jm];  w2.y = -w2.y;
            float2 w3 = cmulf(w1, w2);
            float2 y0 = f2add(b0, b1);
            float2 pi_ = make_float2(b2.x - b3.y, b2.y + b3.x);
            float2 mi = make_float2(b2.x + b3.y, b2.y - b3.x);
            dst[4 * jm + kk]         = y0;
            dst[4 * jm + kk + m]     = cmulf(pi_, w1);
            dst[4 * jm + kk + 2 * m] = cmulf(f2sub(b0, b1), w2);
            dst[4 * jm + kk + 3 * m] = cmulf(mi, w3);
        }
        __syncthreads();
        float2* t0 = src; src = dst; dst = t0;
    }
    float* ph1 = phases + (size_t)b1 * TN;
    float* ph2 = phases + (size_t)b2 * TN;
    for (int i = tid; i < TN; i += HT) {
        float2 d = src[i];
        float x1v = xr1[i];
        float x2v = xr2[i];
        atomicAdd(&ph1[i], atan2f(d.y - x2v, x1v) * (1.0f / 9.0f));
        atomicAdd(&ph2[i], atan2f(x1v - d.x, x2v) * (1.0f / 9.0f));
    }
}

// feat: writes f16 hi/lo point fragment tiles (aunit layout) into out_q region.
__global__ __launch_bounds__(256) void feat_kernel(
    const float* __restrict__ imu,
    const float* __restrict__ Wm, const float* __restrict__ bm,
    const float* __restrict__ Wp, const float* __restrict__ bp,
    const float* __restrict__ phases,
    f16x8* __restrict__ atiles) {
    const int p = blockIdx.x * 256 + threadIdx.x;
    const int bb = p >> 12;
    const int tt = p & (TN - 1);
    float xc[9];
    #pragma unroll
    for (int c = 0; c < 9; ++c)
        xc[c] = imu[((size_t)(bb * 9 + c)) * TN + tt];
    float sp, cp;
    sincosf(phases[p], &sp, &cp);

    const int pbase = p >> 4;
    const int l15 = p & 15;
    #pragma unroll
    for (int g = 0; g < 8; ++g) {
        float v8[8];
        if (g < 4) {
            #pragma unroll
            for (int e = 0; e < 8; ++e) {
                const int j = 8 * g + e;
                float a = bm[j];
                #pragma unroll
                for (int c = 0; c < 9; ++c) a = fmaf(Wm[j * 9 + c], xc[c], a);
                v8[e] = a;
            }
        } else {
            #pragma unroll
            for (int e = 0; e < 8; ++e) {
                const int j = 8 * (g - 4) + e;
                float a = bp[j];
                #pragma unroll
                for (int c = 0; c < 7; ++c) a = fmaf(Wp[j * 9 + c], xc[c], a);
                a = fmaf(Wp[j * 9 + 7], cp, a);
                a = fmaf(Wp[j * 9 + 8], sp, a);
                v8[e] = a;
            }
        }
        f16x8 hv, lv;
        #pragma unroll
        for (int e = 0; e < 8; ++e) {
            _Float16 hh = (_Float16)v8[e];
            hv[e] = hh;
            lv[e] = (_Float16)(v8[e] - (float)hh);
        }
        const int s = g >> 2;
        const int hi16 = g & 3;
        atiles[aunit(pbase, 0, s, hi16, l15)] = hv;
        atiles[aunit(pbase, 1, s, hi16, l15)] = lv;
    }
}

#define MFMA16(A, B, C) __builtin_amdgcn_mfma_f32_16x16x32_f16((A), (B), (C), 0, 0, 0)

// vq r12: 512 blocks x 512 thr (8 waves), 256 pts/block. Wave owns ALL 64
// of its codes in regs (single pass); the block's 64KB of point tiles are
// staged ONCE into LDS via global_load_lds, then B-frags are conflict-free
// ds_read_b128 shared by all 8 waves (no global loads, no barriers in loop).
// launch_bounds(512,2): VGPR cap 256 (est ~130, no spill); LDS-bound 1 blk/CU.
__global__ __launch_bounds__(VQT, 2) void vq_kernel(
    const float* __restrict__ imu,
    const float* __restrict__ Wm, const float* __restrict__ bm,
    const float* __restrict__ Wp, const float* __restrict__ bp,
    const float* __restrict__ cb,
    const float* __restrict__ cn,
    const f16x8* __restrict__ ctiles,
    const float* __restrict__ phases,
    const f16x8* atiles,           // aliases out_q (no __restrict__)
    float* out_q,
    float* __restrict__ out_i) {
    __shared__ __align__(16) f16x8 sPT[16 * 256];   // 64 KB point tiles
    __shared__ float s_b[8][PTS];                   // 8 KB
    __shared__ float s_s[8][PTS];                   // 8 KB
    __shared__ int   s_i[8][PTS];                   // 8 KB
    __shared__ int s_idx[PTS];
    __shared__ float s_gap[PTS];
    const int tid = threadIdx.x;
    const int lane = tid & 63;
    const int w = tid >> 6;          // 8 waves
    const int l15 = lane & 15;
    const int hi16 = lane >> 4;
    const int p0 = blockIdx.x * PTS;
    const int pb0 = p0 >> 4;

    // ---- stage the block's 64KB of point tiles into LDS (bulk DMA) ----
    {
        const char* gsrc = (const char*)(atiles + (size_t)pb0 * 256);
        char* ldst = (char*)sPT;
        #pragma unroll
        for (int i = 0; i < 8; ++i) {
            const int u = i * VQT + tid;
            gload_lds16(gsrc + (size_t)u * 16, ldst + u * 16);
        }
    }

    // ---- this wave's 64 codes: 16 fragments + norms, loaded to regs ----
    const int kbase = 64 * w;
    f16x8 cH[4][2], cL[4][2];
    #pragma unroll
    for (int rf = 0; rf < 4; ++rf) {
        #pragma unroll
        for (int s = 0; s < 2; ++s) {
            cH[rf][s] = ctiles[aunit(4 * w + rf, 0, s, hi16, l15)];
            cL[rf][s] = ctiles[aunit(4 * w + rf, 1, s, hi16, l15)];
        }
    }
    f32x4 cnv[4];
    #pragma unroll
    for (int rf = 0; rf < 4; ++rf)
        cnv[rf] = *(const f32x4*)(cn + kbase + 16 * rf + 4 * hi16);
    __syncthreads();   // drains staging DMA (vmcnt) before LDS reads

    for (int cf = 0; cf < 16; ++cf) {
        // B-frags: contiguous 1KB ds_read_b128 per frag (conflict-free)
        f16x8 bH0 = sPT[cf * 256 + 0 * 128 + 0 * 64 + lane];
        f16x8 bH1 = sPT[cf * 256 + 0 * 128 + 1 * 64 + lane];
        f16x8 bL0 = sPT[cf * 256 + 1 * 128 + 0 * 64 + lane];
        f16x8 bL1 = sPT[cf * 256 + 1 * 128 + 1 * 64 + lane];
        f32x4 acc[4];
        #pragma unroll
        for (int rf = 0; rf < 4; ++rf) acc[rf] = (f32x4){0.f, 0.f, 0.f, 0.f};
        #pragma unroll
        for (int rf = 0; rf < 4; ++rf) {
            acc[rf] = MFMA16(cH[rf][0], bH0, acc[rf]);
            acc[rf] = MFMA16(cH[rf][0], bL0, acc[rf]);
            acc[rf] = MFMA16(cL[rf][0], bH0, acc[rf]);
            acc[rf] = MFMA16(cH[rf][1], bH1, acc[rf]);
            acc[rf] = MFMA16(cH[rf][1], bL1, acc[rf]);
            acc[rf] = MFMA16(cL[rf][1], bH1, acc[rf]);
        }
        // C layout: row (code) = 16rf+4hi16+r, col (point) = 16cf+l15.
        // in-lane top-2 over 16 candidates (ascending code order, strict <)
        float b = 3.4e38f, sec = 3.4e38f;
        int bi = 0;
        #pragma unroll
        for (int rf = 0; rf < 4; ++rf) {
            #pragma unroll
            for (int r = 0; r < 4; ++r) {
                float sc = fmaf(-2.0f, acc[rf][r], cnv[rf][r]);
                const int ci = kbase + 16 * rf + 4 * hi16 + r;
                bool lt = sc < b;
                sec = fminf(sec, lt ? b : sc);
                b = lt ? sc : b;
                bi = lt ? ci : bi;
            }
        }
        // cross-hi16 merge (masks 16, 32), tie -> smaller index
        #pragma unroll
        for (int m = 16; m <= 32; m <<= 1) {
            float ob = __shfl_xor(b, m, 64);
            float os = __shfl_xor(sec, m, 64);
            int oi = __shfl_xor(bi, m, 64);
            float mx = fmaxf(b, ob);
            sec = fminf(fminf(sec, os), mx);
            bool take = (ob < b) || (ob == b && oi < bi);
            b = take ? ob : b;
            bi = take ? oi : bi;
        }
        if (hi16 == 0) {
            s_b[w][16 * cf + l15] = b;
            s_s[w][16 * cf + l15] = sec;
            s_i[w][16 * cf + l15] = bi;
        }
    }
    __syncthreads();

    // ---- block merge: 8 wave-partials per point (ascending code ranges) ----
    if (tid < PTS) {
        float b = 3.4e38f, sec = 3.4e38f;
        int bi = 0;
        #pragma unroll 4
        for (int q = 0; q < 8; ++q) {
            float ob = s_b[q][tid];
            float os = s_s[q][tid];
            int oi = s_i[q][tid];
            float mx = fmaxf(b, ob);
            sec = fminf(fminf(sec, os), mx);
            bool take = (ob < b) || (ob == b && oi < bi);
            b = take ? ob : b;
            bi = take ? oi : bi;
        }
        s_idx[tid] = bi;
        out_i[p0 + tid] = (float)bi;
        s_gap[tid] = sec - b;
    }
    __syncthreads();

    // ---- rare exact f32 rescan (streaming feature recompute) ----
    {
        bool fl = (lane < 32) && (s_gap[32 * w + (lane & 31)] < TAU);
        unsigned long long bal = __ballot(fl);
        while (bal) {
            const int ln = __builtin_ctzll(bal);
            bal &= bal - 1;
            const int row = 32 * w + ln;
            const int pR = p0 + row;
            const int bbR = pR >> 12;
            const int ttR = pR & (TN - 1);
            float xcR[9];
            #pragma unroll
            for (int c = 0; c < 9; ++c)
                xcR[c] = imu[((size_t)(bbR * 9 + c)) * TN + ttR];
            float spR, cpR;
            sincosf(phases[pR], &spR, &cpR);
            float a0[8], a1[8], a2[8], a3[8];
            #pragma unroll
            for (int cc = 0; cc < 8; ++cc) {
                a0[cc] = 0.f; a1[cc] = 0.f; a2[cc] = 0.f; a3[cc] = 0.f;
            }
            for (int d4 = 0; d4 < 16; ++d4) {
                float fd[4];
                #pragma unroll
                for (int e = 0; e < 4; ++e) {
                    const int j = 4 * d4 + e;
                    float a;
                    if (j < 32) {
                        a = bm[j];
                        #pragma unroll
                        for (int c = 0; c < 9; ++c) a = fmaf(Wm[j * 9 + c], xcR[c], a);
                    } else {
                        const int jj = j - 32;
                        a = bp[jj];
                        #pragma unroll
                        for (int c = 0; c < 7; ++c) a = fmaf(Wp[jj * 9 + c], xcR[c], a);
                        a = fmaf(Wp[jj * 9 + 7], cpR, a);
                        a = fmaf(Wp[jj * 9 + 8], spR, a);
                    }
                    fd[e] = a;
                }
                #pragma unroll
                for (int cc = 0; cc < 8; ++cc) {
                    const float4 cv = ((const float4*)(cb + (size_t)(lane * 8 + cc) * CDIM))[d4];
                    a0[cc] = fmaf(fd[0], cv.x, a0[cc]);
                    a1[cc] = fmaf(fd[1], cv.y, a1[cc]);
                    a2[cc] = fmaf(fd[2], cv.z, a2[cc]);
                    a3[cc] = fmaf(fd[3], cv.w, a3[cc]);
                }
            }
            unsigned long long pbest = ~0ull;
            #pragma unroll
            for (int cc = 0; cc < 8; ++cc) {
                const int kk = lane * 8 + cc;
                float sc = fmaf(-2.0f, (a0[cc] + a1[cc]) + (a2[cc] + a3[cc]), cn[kk]);
                unsigned long long pk = packsi(sc, kk);
                pbest = pk < pbest ? pk : pbest;
            }
            #pragma unroll
            for (int m = 1; m <= 32; m <<= 1) {
                unsigned long long o = __shfl_xor(pbest, m, 64);
                pbest = o < pbest ? o : pbest;
            }
            if (lane == 0) {
                const int bi = (int)(pbest & 0xFFFFFFFFu);
                s_idx[row] = bi;
                out_i[p0 + row] = (float)bi;
            }
        }
    }
    __syncthreads();

    // ---- cooperative coalesced gather of quantized rows (L2-hot cb) ----
    float4* oq = (float4*)out_q;
    const float4* c4g = (const float4*)cb;
    for (int i = tid; i < PTS * 16; i += VQT) {
        const int pt = i >> 4;
        const int q = i & 15;
        oq[(size_t)(p0 + pt) * 16 + q] = c4g[(size_t)s_idx[pt] * 16 + q];
    }
}

extern "C" void kernel_launch(void* const* d_in, const int* in_sizes, int n_in,
                              void* d_out, int out_size, void* d_ws, size_t ws_size,
                              hipStream_t stream) {
    const float* imu = (const float*)d_in[0];
    const float* Wm  = (const float*)d_in[1];
    const float* bm  = (const float*)d_in[2];
    const float* Wp  = (const float*)d_in[3];
    const float* bp  = (const float*)d_in[4];
    const float* cb  = (const float*)d_in[5];

    float* out_q = (float*)d_out;                          // (32,4096,64)
    float* out_i = out_q + (size_t)NB * TN * CDIM;         // (32,4096) as float
    float* out_p = out_i + (size_t)NB * TN;                // (32,4096) phases

    float* cn     = (float*)d_ws;                          // 512 f32
    f16x8* ctiles = (f16x8*)((char*)d_ws + 2048);          // 128 KB code tiles
    f16x8* atiles = (f16x8*)out_q;                         // point tiles in out_q

    prep_kernel<<<545, 256, 0, stream>>>(cb, cn, ctiles, out_p);
    hilbert_phase_kernel<<<NB * NCH / 2, HT, 0, stream>>>(imu, out_p);
    feat_kernel<<<(NB * TN) / 256, 256, 0, stream>>>(imu, Wm, bm, Wp, bp, out_p, atiles);
    vq_kernel<<<(NB * TN) / PTS, VQT, 0, stream>>>(imu, Wm, bm, Wp, bp, cb,
                                                   cn, ctiles, out_p, atiles,
                                                   out_q, out_i);
}